// Round 11
// baseline (183.208 us; speedup 1.0000x reference)
//
#include <hip/hip_runtime.h>

#define GCN_N 100000
#define GCN_H 128
#define GCN_G 256
#define NPB_SHIFT 9                    // 512 nodes per bucket
#define NPB 512
#define NBKT 196                       // ceil(100000/512)
#define CHUNK 2048                     // edges per hist/partition block
#define SRC_BITS 17
#define SRC_MASK ((1 << SRC_BITS) - 1)
#define EBUF_CAP 10240                 // LDS staging for csr_build

static_assert(GCN_N < (1 << SRC_BITS), "src id must fit 17 bits");

using short8 = __attribute__((ext_vector_type(8))) short;
using f32x4  = __attribute__((ext_vector_type(4))) float;
using f32x2  = __attribute__((ext_vector_type(2))) float;

#if defined(__has_builtin)
#if __has_builtin(__builtin_amdgcn_cvt_scalef32_pk_f32_fp4)
#define HW_FP4 1
#endif
#endif

// ---------------- bf16 / fp4 helpers ----------------

__device__ __forceinline__ unsigned short f2bf(float f) {
    unsigned u = __float_as_uint(f);
    unsigned r = u + 0x7FFFu + ((u >> 16) & 1u);   // round to nearest even
    return (unsigned short)(r >> 16);
}
__device__ __forceinline__ float bf2f(unsigned short h) {
    return __uint_as_float(((unsigned)h) << 16);
}

// decode 8 fp4(e2m1) packed in a dword -> 8 floats (unscaled)
__device__ __forceinline__ void fp4x8_to_f32(unsigned v, float* f) {
#ifdef HW_FP4
    f32x2 p0 = __builtin_amdgcn_cvt_scalef32_pk_f32_fp4(v, 1.0f, 0);
    f32x2 p1 = __builtin_amdgcn_cvt_scalef32_pk_f32_fp4(v, 1.0f, 1);
    f32x2 p2 = __builtin_amdgcn_cvt_scalef32_pk_f32_fp4(v, 1.0f, 2);
    f32x2 p3 = __builtin_amdgcn_cvt_scalef32_pk_f32_fp4(v, 1.0f, 3);
    f[0] = p0[0]; f[1] = p0[1]; f[2] = p1[0]; f[3] = p1[1];
    f[4] = p2[0]; f[5] = p2[1]; f[6] = p3[0]; f[7] = p3[1];
#else
    #pragma unroll
    for (int j = 0; j < 8; j++) {
        unsigned nib = (v >> (4 * j)) & 0xF;
        unsigned e = (nib >> 1) & 3, m = nib & 1;
        float mag = (e == 0) ? 0.5f * (float)m : ldexpf(1.0f + 0.5f * (float)m, (int)e - 1);
        f[j] = (nib & 8) ? -mag : mag;
    }
#endif
}

// encode v/scale (|v/scale|<=6) to e2m1 nibble (software, semantics-safe)
__device__ __forceinline__ unsigned f32_to_fp4(float a) {
    unsigned sg = (a < 0.f) ? 8u : 0u;
    float b = fabsf(a);
    unsigned q = (unsigned)(b >= 0.25f) + (unsigned)(b >= 0.75f) + (unsigned)(b >= 1.25f)
               + (unsigned)(b >= 1.75f) + (unsigned)(b >= 2.5f) + (unsigned)(b >= 3.5f)
               + (unsigned)(b >= 5.0f);
    return sg | q;
}

// ---------------- hist + prep (fused) ----------------
// blocks [0,B): per-block dst histogram; [B,B+64): W1^T->bf16; B+64: w2l+c2

__global__ __launch_bounds__(256) void hist_prep_kernel(const int* __restrict__ dst,
                                                        int* __restrict__ hist, int E, int B,
                                                        const float* __restrict__ W1,
                                                        const float* __restrict__ W2,
                                                        const float* __restrict__ b2,
                                                        const float* __restrict__ lw,
                                                        unsigned short* __restrict__ w1t,
                                                        float* __restrict__ w2l,
                                                        float* __restrict__ c2) {
    __shared__ int lh[NBKT];
    __shared__ float slw[128];
    int blk = blockIdx.x, tid = threadIdx.x;
    if (blk < B) {
        if (tid < NBKT) lh[tid] = 0;
        __syncthreads();
        int e0 = blk * CHUNK;
        #pragma unroll
        for (int i = 0; i < CHUNK / 256; i++) {
            int e = e0 + tid + i * 256;
            if (e < E) atomicAdd(&lh[dst[e] >> NPB_SHIFT], 1);
        }
        __syncthreads();
        if (tid < NBKT) hist[(size_t)blk * NBKT + tid] = lh[tid];
    } else if (blk < B + 64) {
        int idx = (blk - B) * 256 + tid;           // 0..16383
        int col = idx >> 7, k = idx & 127;
        w1t[idx] = f2bf(W1[k * 128 + col]);
    } else {
        if (tid < 128) slw[tid] = lw[tid];
        __syncthreads();
        if (tid < 128) {
            float s = 0.f;
            #pragma unroll 8
            for (int j = 0; j < 128; j++) s = fmaf(W2[tid * 128 + j], slw[j], s);
            w2l[tid] = s;
        } else if (tid == 128) {
            float s = 0.f;
            for (int j = 0; j < 128; j++) s = fmaf(b2[j], slw[j], s);
            c2[0] = s;
        }
    }
}

__global__ __launch_bounds__(64) void scan_cols_kernel(const int* __restrict__ hist,
                                                       int* __restrict__ offsT,
                                                       int* __restrict__ btot, int B) {
    int k = blockIdx.x;
    int lane = threadIdx.x;
    int running = 0;
    for (int b0 = 0; b0 < B; b0 += 64) {
        int b = b0 + lane;
        int v = (b < B) ? hist[(size_t)b * NBKT + k] : 0;
        int iv = v;
        #pragma unroll
        for (int d = 1; d < 64; d <<= 1) {
            int x = __shfl_up(iv, d, 64);
            if (lane >= d) iv += x;
        }
        if (b < B) offsT[(size_t)k * B + b] = running + iv - v;   // exclusive
        running += __shfl(iv, 63, 64);
    }
    if (lane == 0) btot[k] = running;
}

// partition: recomputes bucket bases from btot in-block
__global__ __launch_bounds__(256) void partition_kernel(const int* __restrict__ src,
                                                        const int* __restrict__ dst,
                                                        const int* __restrict__ btot,
                                                        const int* __restrict__ offsT,
                                                        int* __restrict__ epack,
                                                        int E, int B) {
    __shared__ int cur[NBKT];
    __shared__ int sbase[NBKT];
    int blk = blockIdx.x, tid = threadIdx.x;
    if (tid == 0) {
        int run = 0;
        for (int kk = 0; kk < NBKT; kk++) { sbase[kk] = run; run += btot[kk]; }
    }
    __syncthreads();
    if (tid < NBKT) cur[tid] = sbase[tid] + offsT[(size_t)tid * B + blk];
    __syncthreads();
    int e0 = blk * CHUNK;
    #pragma unroll
    for (int i = 0; i < CHUNK / 256; i++) {
        int e = e0 + tid + i * 256;
        if (e < E) {
            int d = dst[e];
            int s = src[e];
            int pos = atomicAdd(&cur[d >> NPB_SHIFT], 1);
            epack[pos] = ((d & (NPB - 1)) << SRC_BITS) | s;
        }
    }
}

// builds local CSR AND writes dis + xsp; LDS-stages its epack slice
__global__ __launch_bounds__(512) void csr_build_kernel(const int* __restrict__ epack,
                                                        const int* __restrict__ btot,
                                                        const float* __restrict__ x,
                                                        int* __restrict__ rowptr,
                                                        float* __restrict__ dis,
                                                        float* __restrict__ xsp,
                                                        int* __restrict__ csrc, int n) {
    __shared__ int ebuf[EBUF_CAP];              // 40 KB
    __shared__ int lcount[NPB];
    __shared__ int lcur[NPB];
    __shared__ int wsums[8];
    __shared__ int s_eb, s_ee, s_tot;
    int k = blockIdx.x, tid = threadIdx.x;
    int lane = tid & 63, wid = tid >> 6;
    int nodebase = k << NPB_SHIFT;

    lcount[tid] = 0;
    if (tid == 0) {
        int run = 0, eb = 0, ee = 0;
        for (int kk = 0; kk < NBKT; kk++) {
            if (kk == k) eb = run;
            run += btot[kk];
            if (kk == k) ee = run;
        }
        s_eb = eb; s_ee = ee; s_tot = run;
    }
    __syncthreads();
    int ebeg = s_eb, eend = s_ee;
    bool fits = (eend - ebeg) <= EBUF_CAP;

    for (int e = ebeg + tid; e < eend; e += 512) {
        int p = epack[e];
        if (fits) ebuf[e - ebeg] = p;
        atomicAdd(&lcount[p >> SRC_BITS], 1);
    }
    __syncthreads();

    int v = lcount[tid];
    int iv = v;
    #pragma unroll
    for (int d = 1; d < 64; d <<= 1) {
        int x2 = __shfl_up(iv, d, 64);
        if (lane >= d) iv += x2;
    }
    if (lane == 63) wsums[wid] = iv;
    __syncthreads();
    if (tid == 0) {
        int r = 0;
        #pragma unroll
        for (int w = 0; w < 8; w++) { int t = wsums[w]; wsums[w] = r; r += t; }
    }
    __syncthreads();
    int ex = wsums[wid] + iv - v;
    lcur[tid] = ex;
    int node = nodebase + tid;
    if (node < n) {
        rowptr[node] = ebeg + ex;
        float dd = rsqrtf((float)(v + 1));       // deg = indeg + self-loop
        dis[node] = dd;
        const float* xr = x + (size_t)node * 5;
        float4 a;
        a.x = xr[0] * dd; a.y = xr[1] * dd; a.z = xr[2] * dd; a.w = xr[3] * dd;
        float a4 = xr[4] * dd;
        ((float4*)(xsp + (size_t)node * 8))[0] = a;
        xsp[(size_t)node * 8 + 4] = a4;
        xsp[(size_t)node * 8 + 5] = 0.f;
        xsp[(size_t)node * 8 + 6] = 0.f;
        xsp[(size_t)node * 8 + 7] = 0.f;
    }
    if (k == NBKT - 1 && tid == 0) rowptr[n] = s_tot;
    __syncthreads();
    for (int e = ebeg + tid; e < eend; e += 512) {
        int p = fits ? ebuf[e - ebeg] : epack[e];
        int pos = atomicAdd(&lcur[p >> SRC_BITS], 1);
        csrc[ebeg + pos] = p & SRC_MASK;
    }
}

// ---------------- layer-0 aggregation (5-dim, standalone, full occupancy) ----------------

__global__ __launch_bounds__(256) void aggx_kernel(const float* __restrict__ xsp,
                                                   const float* __restrict__ dis,
                                                   const int* __restrict__ rowptr,
                                                   const int* __restrict__ csrc,
                                                   float* __restrict__ a0p, int n) {
    int i = blockIdx.x * 256 + threadIdx.x;
    if (i >= n) return;
    float4 acc = ((const float4*)(xsp + (size_t)i * 8))[0];
    float acc4 = xsp[(size_t)i * 8 + 4];
    int r0 = rowptr[i], r1 = rowptr[i + 1];
    int e = r0;
    for (; e + 7 < r1; e += 8) {
        int ss[8];
        #pragma unroll
        for (int u = 0; u < 8; u++) ss[u] = csrc[e + u];
        float4 v[8]; float a4[8];
        #pragma unroll
        for (int u = 0; u < 8; u++) {
            v[u] = ((const float4*)(xsp + (size_t)ss[u] * 8))[0];
            a4[u] = xsp[(size_t)ss[u] * 8 + 4];
        }
        #pragma unroll
        for (int u = 0; u < 8; u++) {
            acc.x += v[u].x; acc.y += v[u].y; acc.z += v[u].z; acc.w += v[u].w;
            acc4 += a4[u];
        }
    }
    for (; e < r1; e++) {
        int s = csrc[e];
        float4 v = ((const float4*)(xsp + (size_t)s * 8))[0];
        acc.x += v.x; acc.y += v.y; acc.z += v.z; acc.w += v.w;
        acc4 += xsp[(size_t)s * 8 + 4];
    }
    float di = dis[i];
    acc.x *= di; acc.y *= di; acc.z *= di; acc.w *= di; acc4 *= di;
    ((float4*)(a0p + (size_t)i * 8))[0] = acc;
    a0p[(size_t)i * 8 + 4] = acc4;
}

// ------- fused mm (MFMA): t1 = fp4_rowscaled( dis ⊙ (relu(a0@W0+b0) @ W1) ) -------

__global__ __launch_bounds__(256) void mmfused_kernel(const float* __restrict__ a0p,
                                                      const float* __restrict__ W0,
                                                      const float* __restrict__ b0,
                                                      const unsigned short* __restrict__ w1t,
                                                      const float* __restrict__ dis,
                                                      unsigned* __restrict__ t1q4,
                                                      float* __restrict__ tscale, int n) {
    __shared__ __align__(16) unsigned short sA[128 * 128];   // 32 KB h1 / reused for out
    __shared__ __align__(16) unsigned short sBT[128 * 128];  // 32 KB W1^T
    __shared__ __align__(16) float4 sA0[256];                // 4 KB a0p rows
    __shared__ float sDis[128];
    __shared__ float sSmax[128];
    char* sAb = (char*)sA;
    char* sBb = (char*)sBT;
    int tid = threadIdx.x;
    int rowBase = blockIdx.x * 128;

    // stage a0p rows + dis (float4, conflict-free)
    {
        int rowL = tid >> 1, q = tid & 1;
        int gr = rowBase + rowL;
        float4 v = make_float4(0.f, 0.f, 0.f, 0.f);
        if (gr < n) v = ((const float4*)a0p)[(size_t)gr * 2 + q];
        sA0[tid] = v;
        if (tid < 128) {
            int g2 = rowBase + tid;
            sDis[tid] = (g2 < n) ? dis[g2] : 0.f;
        }
    }
    // stage w1t (bf16, pre-transposed) -> sBT swizzled, ds_write_b128
    #pragma unroll
    for (int it = 0; it < 8; it++) {
        int idx = tid + it * 256;           // uint4 index, 0..2047
        int col = idx >> 4, c = idx & 15;   // c: 16B chunk = 8 k-values
        uint4 v = ((const uint4*)w1t)[idx];
        int byteoff = (col * 256 + c * 16) ^ ((col & 7) << 4);
        *(uint4*)(sBb + byteoff) = v;
    }
    __syncthreads();

    // h1 = relu(a0 @ W0 + b0) -> sA bf16, swizzled
    {
        int cq = tid & 31;
        int rg = tid >> 5;
        float4 w0q[5];
        #pragma unroll
        for (int j = 0; j < 5; j++) w0q[j] = *((const float4*)(W0 + j * 128 + cq * 4));
        float4 b0q = *((const float4*)(b0 + cq * 4));
        const float* sA0f = (const float*)sA0;
        #pragma unroll
        for (int ri = 0; ri < 16; ri++) {
            int row = rg + ri * 8;
            const float* ar = sA0f + row * 8;
            float4 h = b0q;
            #pragma unroll
            for (int j = 0; j < 5; j++) {
                float aj = ar[j];
                h.x = fmaf(aj, w0q[j].x, h.x);
                h.y = fmaf(aj, w0q[j].y, h.y);
                h.z = fmaf(aj, w0q[j].z, h.z);
                h.w = fmaf(aj, w0q[j].w, h.w);
            }
            h.x = fmaxf(h.x, 0.f); h.y = fmaxf(h.y, 0.f);
            h.z = fmaxf(h.z, 0.f); h.w = fmaxf(h.w, 0.f);
            uint2 p;
            p.x = (unsigned)f2bf(h.x) | ((unsigned)f2bf(h.y) << 16);
            p.y = (unsigned)f2bf(h.z) | ((unsigned)f2bf(h.w) << 16);
            int byteoff = (row * 256 + cq * 8) ^ ((row & 7) << 4);
            *(uint2*)(sAb + byteoff) = p;
        }
    }
    __syncthreads();

    int wave = tid >> 6, l = tid & 63;
    int lr = l & 15, lg = l >> 4;
    int rb = wave * 32;

    short8 afr[2][4];
    #pragma unroll
    for (int rt = 0; rt < 2; rt++) {
        int row = rb + rt * 16 + lr;
        #pragma unroll
        for (int ks = 0; ks < 4; ks++) {
            int byteoff = (row * 256 + ks * 64 + lg * 16) ^ ((row & 7) << 4);
            afr[rt][ks] = *(const short8*)(sAb + byteoff);
        }
    }
    f32x4 acc[2][8];
    #pragma unroll
    for (int rt = 0; rt < 2; rt++)
        #pragma unroll
        for (int ct = 0; ct < 8; ct++)
            acc[rt][ct] = (f32x4){0.f, 0.f, 0.f, 0.f};

    #pragma unroll
    for (int ct = 0; ct < 8; ct++) {
        int col = ct * 16 + lr;
        short8 bfr[4];
        #pragma unroll
        for (int ks = 0; ks < 4; ks++) {
            int byteoff = (col * 256 + ks * 64 + lg * 16) ^ ((col & 7) << 4);
            bfr[ks] = *(const short8*)(sBb + byteoff);
        }
        #pragma unroll
        for (int rt = 0; rt < 2; rt++) {
            #pragma unroll
            for (int ks = 0; ks < 4; ks++) {
                acc[rt][ct] = __builtin_amdgcn_mfma_f32_16x16x32_bf16(
                    afr[rt][ks], bfr[ks], acc[rt][ct], 0, 0, 0);
            }
        }
    }

    // epilogue: dis-scale, bf16 into sA, per-row absmax via 16-lane shfl_xor reduce
    #pragma unroll
    for (int rt = 0; rt < 2; rt++) {
        #pragma unroll
        for (int i = 0; i < 4; i++) {
            int rowL = rb + rt * 16 + lg * 4 + i;
            float dsc = sDis[rowL];
            float m = 0.f;
            #pragma unroll
            for (int ct = 0; ct < 8; ct++) {
                int col = ct * 16 + lr;
                float vv = acc[rt][ct][i] * dsc;
                int byteoff = (rowL * 256 + col * 2) ^ ((rowL & 7) << 4);
                *(unsigned short*)(sAb + byteoff) = f2bf(vv);
                m = fmaxf(m, fabsf(vv));
            }
            #pragma unroll
            for (int msk = 1; msk < 16; msk <<= 1)
                m = fmaxf(m, __shfl_xor(m, msk, 64));
            if (lr == 0) sSmax[rowL] = m;
        }
    }
    __syncthreads();

    // copy-out: bf16 -> fp4 e2m1 with per-row scale; 8 cols -> 1 dword
    #pragma unroll
    for (int it = 0; it < 8; it++) {
        int flat = tid + it * 256;
        int rowL = flat >> 4, c16 = flat & 15;
        int gr = rowBase + rowL;
        if (gr < n) {
            int byteoff = (rowL * 256 + c16 * 16) ^ ((rowL & 7) << 4);
            uint4 v = *(const uint4*)(sAb + byteoff);
            float ff[8];
            ff[0] = __uint_as_float(v.x << 16); ff[1] = __uint_as_float(v.x & 0xFFFF0000u);
            ff[2] = __uint_as_float(v.y << 16); ff[3] = __uint_as_float(v.y & 0xFFFF0000u);
            ff[4] = __uint_as_float(v.z << 16); ff[5] = __uint_as_float(v.z & 0xFFFF0000u);
            ff[6] = __uint_as_float(v.w << 16); ff[7] = __uint_as_float(v.w & 0xFFFF0000u);
            float s6 = sSmax[rowL] * (1.f / 6.f);
            float inv = (s6 > 0.f) ? 1.f / s6 : 0.f;
            unsigned q = 0;
            #pragma unroll
            for (int j = 0; j < 8; j++) q |= f32_to_fp4(ff[j] * inv) << (4 * j);
            t1q4[(size_t)gr * 16 + c16] = q;
            if (c16 == 0) tscale[gr] = s6;
        }
    }
}

// --------- layer-1 aggregation (fp4 gather, 64 B/row) + layer-2 dot ---------

__global__ __launch_bounds__(256) void agg1_kernel(const unsigned* __restrict__ t1q4,
                                                   const float* __restrict__ tscale,
                                                   const float* __restrict__ dis,
                                                   const int* __restrict__ rowptr,
                                                   const int* __restrict__ csrc,
                                                   const float* __restrict__ b1,
                                                   const float* __restrict__ w2l,
                                                   float* __restrict__ z, int n) {
    int group = threadIdx.x >> 4, lane = threadIdx.x & 15;
    int i = blockIdx.x * 16 + group;
    if (i >= n) return;
    float f[8], acc[8];
    unsigned sv = t1q4[(size_t)i * 16 + lane];
    float sci = tscale[i];
    fp4x8_to_f32(sv, f);
    #pragma unroll
    for (int j = 0; j < 8; j++) acc[j] = f[j] * sci;
    int r0 = rowptr[i], r1 = rowptr[i + 1];
    for (int e = r0; e < r1; e += 16) {
        int cnt = r1 - e; if (cnt > 16) cnt = 16;   // uniform within group
        int idx = e + lane;
        int si = (idx < r1) ? csrc[idx] : 0;        // coalesced index load
        unsigned vv[16]; float sc[16];
        #pragma unroll
        for (int u = 0; u < 16; u++) {
            if (u < cnt) {
                int s = __shfl(si, u, 16);
                vv[u] = t1q4[(size_t)s * 16 + lane]; // one 64-B line per row
                sc[u] = tscale[s];
            }
        }
        #pragma unroll
        for (int u = 0; u < 16; u++) {
            if (u < cnt) {
                fp4x8_to_f32(vv[u], f);
                #pragma unroll
                for (int j = 0; j < 8; j++) acc[j] = fmaf(f[j], sc[u], acc[j]);
            }
        }
    }
    float di = dis[i];
    float4 b4a = ((const float4*)b1)[lane * 2];
    float4 b4b = ((const float4*)b1)[lane * 2 + 1];
    float4 w4a = ((const float4*)w2l)[lane * 2];
    float4 w4b = ((const float4*)w2l)[lane * 2 + 1];
    float bb[8] = {b4a.x, b4a.y, b4a.z, b4a.w, b4b.x, b4b.y, b4b.z, b4b.w};
    float ww[8] = {w4a.x, w4a.y, w4a.z, w4a.w, w4b.x, w4b.y, w4b.z, w4b.w};
    float d = 0.f;
    #pragma unroll
    for (int j = 0; j < 8; j++) {
        float c = fmaxf(fmaf(di, acc[j], bb[j]), 0.f);
        d = fmaf(c, ww[j], d);
    }
    #pragma unroll
    for (int o = 8; o > 0; o >>= 1) d += __shfl_down(d, o, 16);
    if (lane == 0) z[i] = di * d;
}

// ------- layer-2 scalar aggregation + pooling + FINAL (last-block) -------

__global__ __launch_bounds__(256) void aggz_pool_kernel(const float* __restrict__ z,
                                                        const float* __restrict__ dis,
                                                        const int* __restrict__ rowptr,
                                                        const int* __restrict__ csrc,
                                                        const int* __restrict__ batch,
                                                        const float* __restrict__ c2,
                                                        const float* __restrict__ lb,
                                                        float* __restrict__ gsum,
                                                        int* __restrict__ gcnt,
                                                        int* __restrict__ done,
                                                        float* __restrict__ out, int n) {
    __shared__ float lg[GCN_G];
    __shared__ int lc[GCN_G];
    __shared__ int sticket;
    int tid = threadIdx.x;
    lg[tid] = 0.f;
    lc[tid] = 0;
    __syncthreads();
    int i = blockIdx.x * 256 + tid;
    bool valid = i < n;
    float ndv = 0.f;
    int g = 0;
    if (valid) {
        float acc = z[i];
        int r0 = rowptr[i], r1 = rowptr[i + 1];
        int e = r0;
        for (; e + 7 < r1; e += 8) {
            int ss[8];
            #pragma unroll
            for (int u = 0; u < 8; u++) ss[u] = csrc[e + u];
            float zv[8];
            #pragma unroll
            for (int u = 0; u < 8; u++) zv[u] = z[ss[u]];
            #pragma unroll
            for (int u = 0; u < 8; u++) acc += zv[u];
        }
        for (; e < r1; e++) acc += z[csrc[e]];
        ndv = dis[i] * acc;
        g = batch[i];
    }
    int lane = tid & 63;
    int g0 = __shfl(g, 0, 64);
    bool uni = __all(g == g0) && __all(valid);
    if (uni) {
        float s = ndv;
        #pragma unroll
        for (int o = 32; o > 0; o >>= 1) s += __shfl_down(s, o, 64);
        if (lane == 0) {
            atomicAdd(&lg[g0], s);
            atomicAdd(&lc[g0], 64);
        }
    } else if (valid) {
        atomicAdd(&lg[g], ndv);
        atomicAdd(&lc[g], 1);
    }
    __syncthreads();
    float v = lg[tid];
    int c = lc[tid];
    if (v != 0.f) atomicAdd(&gsum[tid], v);
    if (c != 0) atomicAdd(&gcnt[tid], c);

    // last-block final: device-scope ticket + atomic reads
    __threadfence();
    if (tid == 0) sticket = atomicAdd(done, 1);
    __syncthreads();
    if (sticket == (int)gridDim.x - 1) {
        float sv = atomicAdd(&gsum[tid], 0.f);
        int cv = atomicAdd(&gcnt[tid], 0);
        float vv = sv / (float)max(cv, 1) + c2[0] + lb[0];
        out[tid] = 1.f / (1.f + expf(-vv));
    }
}

// ---------------- launch ----------------

extern "C" void kernel_launch(void* const* d_in, const int* in_sizes, int n_in,
                              void* d_out, int out_size, void* d_ws, size_t ws_size,
                              hipStream_t stream) {
    const float* x   = (const float*)d_in[0];
    const int*   ei  = (const int*)d_in[1];
    const int*   bat = (const int*)d_in[2];
    const float* W0  = (const float*)d_in[3];
    const float* b0  = (const float*)d_in[4];
    const float* W1  = (const float*)d_in[5];
    const float* b1  = (const float*)d_in[6];
    const float* W2  = (const float*)d_in[7];
    const float* b2  = (const float*)d_in[8];
    const float* lw  = (const float*)d_in[9];
    const float* lb  = (const float*)d_in[10];
    float* out = (float*)d_out;

    const int N = GCN_N;
    const int E = in_sizes[1] / 2;
    const int B = (E + CHUNK - 1) / CHUNK;

    char* ws = (char*)d_ws;
    size_t off = 0;
    auto alloc = [&](size_t bytes) {
        size_t o = off;
        off += (bytes + 255) & ~(size_t)255;
        return o;
    };
    int*   hist    = (int*)(ws + alloc((size_t)B * NBKT * 4));
    int*   offsT   = (int*)(ws + alloc((size_t)NBKT * B * 4));
    int*   btot    = (int*)(ws + alloc((size_t)NBKT * 4));
    int*   epack   = (int*)(ws + alloc((size_t)E * 4));
    int*   rowptr  = (int*)(ws + alloc((size_t)(N + 1) * 4));
    float* dis     = (float*)(ws + alloc((size_t)N * 4));
    int*   csrc    = (int*)(ws + alloc((size_t)E * 4));
    float* xsp     = (float*)(ws + alloc((size_t)N * 8 * 4));
    float* a0p     = (float*)(ws + alloc((size_t)N * 8 * 4));
    unsigned* t1q4 = (unsigned*)(ws + alloc((size_t)N * 64));   // 64 B/row fp4
    float* tscale  = (float*)(ws + alloc((size_t)N * 4));
    float* z       = (float*)(ws + alloc((size_t)N * 4));
    float* w2l     = (float*)(ws + alloc(128 * 4));
    float* c2      = (float*)(ws + alloc(4));
    unsigned short* w1t = (unsigned short*)(ws + alloc(128 * 128 * 2));
    float* gsum    = (float*)(ws + alloc(GCN_G * 4));   // gsum | gcnt | done contiguous
    int*   gcnt    = (int*)(ws + alloc(GCN_G * 4));
    int*   done    = (int*)(ws + alloc(4));

    const int* src = ei;
    const int* dst = ei + E;

    hipMemsetAsync(gsum, 0, GCN_G * 4 * 2 + 256, stream);   // gsum + gcnt + done

    hist_prep_kernel<<<B + 65, 256, 0, stream>>>(dst, hist, E, B, W1, W2, b2, lw, w1t, w2l, c2);
    scan_cols_kernel<<<NBKT, 64, 0, stream>>>(hist, offsT, btot, B);
    partition_kernel<<<B, 256, 0, stream>>>(src, dst, btot, offsT, epack, E, B);
    csr_build_kernel<<<NBKT, 512, 0, stream>>>(epack, btot, x, rowptr, dis, xsp, csrc, N);

    aggx_kernel<<<(N + 255) / 256, 256, 0, stream>>>(xsp, dis, rowptr, csrc, a0p, N);
    mmfused_kernel<<<(N + 127) / 128, 256, 0, stream>>>(a0p, W0, b0, w1t, dis, t1q4, tscale, N);
    agg1_kernel<<<(N + 15) / 16, 256, 0, stream>>>(t1q4, tscale, dis, rowptr, csrc, b1, w2l, z, N);
    aggz_pool_kernel<<<(N + 255) / 256, 256, 0, stream>>>(z, dis, rowptr, csrc, bat, c2, lb,
                                                          gsum, gcnt, done, out, N);
}

// Round 12
// 175.580 us; speedup vs baseline: 1.0434x; 1.0434x over previous
//
#include <hip/hip_runtime.h>
#include <hip/hip_fp8.h>

#define GCN_N 100000
#define GCN_H 128
#define GCN_G 256
#define NPB_SHIFT 9                    // 512 nodes per bucket
#define NPB 512
#define NBKT 196                       // ceil(100000/512)
#define CHUNK 2048                     // edges per hist/partition block
#define SRC_BITS 17
#define SRC_MASK ((1 << SRC_BITS) - 1)
#define T1_SCALE 256.0f
#define T1_INV_SCALE (1.0f / 256.0f)
#define EBUF_CAP 10240                 // LDS staging for csr_build

static_assert(GCN_N < (1 << SRC_BITS), "src id must fit 17 bits");

using short8 = __attribute__((ext_vector_type(8))) short;
using f32x4  = __attribute__((ext_vector_type(4))) float;
using f32x2  = __attribute__((ext_vector_type(2))) float;

#if defined(__has_builtin)
#if __has_builtin(__builtin_amdgcn_cvt_pk_f32_fp8) && __has_builtin(__builtin_amdgcn_cvt_pk_fp8_f32)
#define HW_FP8 1
#endif
#endif

// ---------------- bf16 / fp8 helpers ----------------

__device__ __forceinline__ unsigned short f2bf(float f) {
    unsigned u = __float_as_uint(f);
    unsigned r = u + 0x7FFFu + ((u >> 16) & 1u);   // round to nearest even
    return (unsigned short)(r >> 16);
}
__device__ __forceinline__ float bf2f(unsigned short h) {
    return __uint_as_float(((unsigned)h) << 16);
}

__device__ __forceinline__ void fp8x4_to_f32(unsigned v, float* f) {
#ifdef HW_FP8
    f32x2 lo = __builtin_amdgcn_cvt_pk_f32_fp8((int)v, false);
    f32x2 hi = __builtin_amdgcn_cvt_pk_f32_fp8((int)v, true);
    f[0] = lo[0]; f[1] = lo[1]; f[2] = hi[0]; f[3] = hi[1];
#else
    #pragma unroll
    for (int j = 0; j < 4; j++) {
        __hip_fp8_e4m3 h;
        h.__x = (unsigned char)((v >> (8 * j)) & 0xFF);
        f[j] = (float)h;
    }
#endif
}

__device__ __forceinline__ unsigned f32x4_to_fp8(float f0, float f1, float f2, float f3) {
#ifdef HW_FP8
    int r = __builtin_amdgcn_cvt_pk_fp8_f32(f0, f1, 0, false);
    r = __builtin_amdgcn_cvt_pk_fp8_f32(f2, f3, r, true);
    return (unsigned)r;
#else
    unsigned r = 0;
    float ff[4] = {f0, f1, f2, f3};
    #pragma unroll
    for (int j = 0; j < 4; j++) {
        __hip_fp8_e4m3 h(ff[j]);
        r |= ((unsigned)h.__x) << (8 * j);
    }
    return r;
#endif
}

// ---------------- hist + prep (fused) ----------------
// blocks [0,B): per-block dst histogram; [B,B+64): W1^T->bf16; B+64: w2l+c2

__global__ __launch_bounds__(256) void hist_prep_kernel(const int* __restrict__ dst,
                                                        int* __restrict__ hist, int E, int B,
                                                        const float* __restrict__ W1,
                                                        const float* __restrict__ W2,
                                                        const float* __restrict__ b2,
                                                        const float* __restrict__ lw,
                                                        unsigned short* __restrict__ w1t,
                                                        float* __restrict__ w2l,
                                                        float* __restrict__ c2) {
    __shared__ int lh[NBKT];
    __shared__ float slw[128];
    int blk = blockIdx.x, tid = threadIdx.x;
    if (blk < B) {
        if (tid < NBKT) lh[tid] = 0;
        __syncthreads();
        int e0 = blk * CHUNK;
        #pragma unroll
        for (int i = 0; i < CHUNK / 256; i++) {
            int e = e0 + tid + i * 256;
            if (e < E) atomicAdd(&lh[dst[e] >> NPB_SHIFT], 1);
        }
        __syncthreads();
        if (tid < NBKT) hist[(size_t)blk * NBKT + tid] = lh[tid];
    } else if (blk < B + 64) {
        int idx = (blk - B) * 256 + tid;           // 0..16383
        int col = idx >> 7, k = idx & 127;
        w1t[idx] = f2bf(W1[k * 128 + col]);
    } else {
        if (tid < 128) slw[tid] = lw[tid];
        __syncthreads();
        if (tid < 128) {
            float s = 0.f;
            #pragma unroll 8
            for (int j = 0; j < 128; j++) s = fmaf(W2[tid * 128 + j], slw[j], s);
            w2l[tid] = s;
        } else if (tid == 128) {
            float s = 0.f;
            for (int j = 0; j < 128; j++) s = fmaf(b2[j], slw[j], s);
            c2[0] = s;
        }
    }
}

// per-bucket column scan; LAST block also scans btot -> bbase (ticket)
__global__ __launch_bounds__(64) void scan_cols_kernel(const int* __restrict__ hist,
                                                       int* __restrict__ offsT,
                                                       int* __restrict__ btot,
                                                       int* __restrict__ bbase,
                                                       int* __restrict__ rowptr,
                                                       int* __restrict__ done2,
                                                       int B, int n) {
    __shared__ int stick;
    int k = blockIdx.x;
    int lane = threadIdx.x;
    int running = 0;
    for (int b0 = 0; b0 < B; b0 += 64) {
        int b = b0 + lane;
        int v = (b < B) ? hist[(size_t)b * NBKT + k] : 0;
        int iv = v;
        #pragma unroll
        for (int d = 1; d < 64; d <<= 1) {
            int x = __shfl_up(iv, d, 64);
            if (lane >= d) iv += x;
        }
        if (b < B) offsT[(size_t)k * B + b] = running + iv - v;   // exclusive
        running += __shfl(iv, 63, 64);
    }
    if (lane == 0) btot[k] = running;
    __threadfence();
    if (lane == 0) stick = atomicAdd(done2, 1);
    __syncthreads();
    if (stick == NBKT - 1) {
        __threadfence();
        int run = 0;
        for (int b0 = 0; b0 < NBKT; b0 += 64) {
            int kk = b0 + lane;
            int v = (kk < NBKT) ? atomicAdd(&btot[kk], 0) : 0;   // coherent read
            int iv = v;
            #pragma unroll
            for (int d = 1; d < 64; d <<= 1) {
                int x = __shfl_up(iv, d, 64);
                if (lane >= d) iv += x;
            }
            if (kk < NBKT) bbase[kk] = run + iv - v;
            run += __shfl(iv, 63, 64);
        }
        if (lane == 0) { bbase[NBKT] = run; rowptr[n] = run; }
    }
}

__global__ __launch_bounds__(256) void partition_kernel(const int* __restrict__ src,
                                                        const int* __restrict__ dst,
                                                        const int* __restrict__ bbase,
                                                        const int* __restrict__ offsT,
                                                        int* __restrict__ epack,
                                                        int E, int B) {
    __shared__ int cur[NBKT];
    int blk = blockIdx.x, tid = threadIdx.x;
    if (tid < NBKT) cur[tid] = bbase[tid] + offsT[(size_t)tid * B + blk];
    __syncthreads();
    int e0 = blk * CHUNK;
    #pragma unroll
    for (int i = 0; i < CHUNK / 256; i++) {
        int e = e0 + tid + i * 256;
        if (e < E) {
            int d = dst[e];
            int s = src[e];
            int pos = atomicAdd(&cur[d >> NPB_SHIFT], 1);
            epack[pos] = ((d & (NPB - 1)) << SRC_BITS) | s;
        }
    }
}

// builds local CSR AND writes dis + xsp; LDS-stages its epack slice
__global__ __launch_bounds__(512) void csr_build_kernel(const int* __restrict__ epack,
                                                        const int* __restrict__ bbase,
                                                        const float* __restrict__ x,
                                                        int* __restrict__ rowptr,
                                                        float* __restrict__ dis,
                                                        float* __restrict__ xsp,
                                                        int* __restrict__ csrc, int n) {
    __shared__ int ebuf[EBUF_CAP];              // 40 KB
    __shared__ int lcount[NPB];
    __shared__ int lcur[NPB];
    __shared__ int wsums[8];
    int k = blockIdx.x, tid = threadIdx.x;
    int lane = tid & 63, wid = tid >> 6;
    int nodebase = k << NPB_SHIFT;
    int ebeg = bbase[k], eend = bbase[k + 1];
    bool fits = (eend - ebeg) <= EBUF_CAP;

    lcount[tid] = 0;
    __syncthreads();
    for (int e = ebeg + tid; e < eend; e += 512) {
        int p = epack[e];
        if (fits) ebuf[e - ebeg] = p;
        atomicAdd(&lcount[p >> SRC_BITS], 1);
    }
    __syncthreads();

    int v = lcount[tid];
    int iv = v;
    #pragma unroll
    for (int d = 1; d < 64; d <<= 1) {
        int x2 = __shfl_up(iv, d, 64);
        if (lane >= d) iv += x2;
    }
    if (lane == 63) wsums[wid] = iv;
    __syncthreads();
    if (tid == 0) {
        int r = 0;
        #pragma unroll
        for (int w = 0; w < 8; w++) { int t = wsums[w]; wsums[w] = r; r += t; }
    }
    __syncthreads();
    int ex = wsums[wid] + iv - v;
    lcur[tid] = ex;
    int node = nodebase + tid;
    if (node < n) {
        rowptr[node] = ebeg + ex;
        float dd = rsqrtf((float)(v + 1));       // deg = indeg + self-loop
        dis[node] = dd;
        const float* xr = x + (size_t)node * 5;
        float4 a;
        a.x = xr[0] * dd; a.y = xr[1] * dd; a.z = xr[2] * dd; a.w = xr[3] * dd;
        float a4 = xr[4] * dd;
        ((float4*)(xsp + (size_t)node * 8))[0] = a;
        xsp[(size_t)node * 8 + 4] = a4;
        xsp[(size_t)node * 8 + 5] = 0.f;
        xsp[(size_t)node * 8 + 6] = 0.f;
        xsp[(size_t)node * 8 + 7] = 0.f;
    }
    __syncthreads();
    for (int e = ebeg + tid; e < eend; e += 512) {
        int p = fits ? ebuf[e - ebeg] : epack[e];
        int pos = atomicAdd(&lcur[p >> SRC_BITS], 1);
        csrc[ebeg + pos] = p & SRC_MASK;
    }
}

// ---------------- layer-0 aggregation (5-dim, 8-deep prefetch) ----------------

__global__ __launch_bounds__(256) void aggx_kernel(const float* __restrict__ xsp,
                                                   const float* __restrict__ dis,
                                                   const int* __restrict__ rowptr,
                                                   const int* __restrict__ csrc,
                                                   float* __restrict__ a0p, int n) {
    int i = blockIdx.x * 256 + threadIdx.x;
    if (i >= n) return;
    float4 acc = ((const float4*)(xsp + (size_t)i * 8))[0];
    float acc4 = xsp[(size_t)i * 8 + 4];
    int r0 = rowptr[i], r1 = rowptr[i + 1];
    int e = r0;
    for (; e + 7 < r1; e += 8) {
        int ss[8];
        #pragma unroll
        for (int u = 0; u < 8; u++) ss[u] = csrc[e + u];
        float4 v[8]; float a4[8];
        #pragma unroll
        for (int u = 0; u < 8; u++) {
            v[u] = ((const float4*)(xsp + (size_t)ss[u] * 8))[0];
            a4[u] = xsp[(size_t)ss[u] * 8 + 4];
        }
        #pragma unroll
        for (int u = 0; u < 8; u++) {
            acc.x += v[u].x; acc.y += v[u].y; acc.z += v[u].z; acc.w += v[u].w;
            acc4 += a4[u];
        }
    }
    for (; e < r1; e++) {
        int s = csrc[e];
        float4 v = ((const float4*)(xsp + (size_t)s * 8))[0];
        acc.x += v.x; acc.y += v.y; acc.z += v.z; acc.w += v.w;
        acc4 += xsp[(size_t)s * 8 + 4];
    }
    float di = dis[i];
    acc.x *= di; acc.y *= di; acc.z *= di; acc.w *= di; acc4 *= di;
    ((float4*)(a0p + (size_t)i * 8))[0] = acc;
    a0p[(size_t)i * 8 + 4] = acc4;
}

// ------- fused mm (MFMA): t1 = fp8( 256 * dis ⊙ (relu(a0@W0 + b0) @ W1) ) -------

__global__ __launch_bounds__(256) void mmfused_kernel(const float* __restrict__ a0p,
                                                      const float* __restrict__ W0,
                                                      const float* __restrict__ b0,
                                                      const unsigned short* __restrict__ w1t,
                                                      const float* __restrict__ dis,
                                                      unsigned* __restrict__ t1f8, int n) {
    __shared__ __align__(16) unsigned short sA[128 * 128];   // 32 KB h1 / reused for out
    __shared__ __align__(16) unsigned short sBT[128 * 128];  // 32 KB W1^T
    __shared__ __align__(16) float4 sA0[256];                // 4 KB a0p rows
    __shared__ float sDis[128];
    char* sAb = (char*)sA;
    char* sBb = (char*)sBT;
    int tid = threadIdx.x;
    int rowBase = blockIdx.x * 128;

    {
        int rowL = tid >> 1, q = tid & 1;
        int gr = rowBase + rowL;
        float4 v = make_float4(0.f, 0.f, 0.f, 0.f);
        if (gr < n) v = ((const float4*)a0p)[(size_t)gr * 2 + q];
        sA0[tid] = v;
        if (tid < 128) {
            int g2 = rowBase + tid;
            sDis[tid] = (g2 < n) ? dis[g2] : 0.f;
        }
    }
    #pragma unroll
    for (int it = 0; it < 8; it++) {
        int idx = tid + it * 256;           // uint4 index, 0..2047
        int col = idx >> 4, c = idx & 15;   // c: 16B chunk = 8 k-values
        uint4 v = ((const uint4*)w1t)[idx];
        int byteoff = (col * 256 + c * 16) ^ ((col & 7) << 4);
        *(uint4*)(sBb + byteoff) = v;
    }
    __syncthreads();

    {
        int cq = tid & 31;
        int rg = tid >> 5;
        float4 w0q[5];
        #pragma unroll
        for (int j = 0; j < 5; j++) w0q[j] = *((const float4*)(W0 + j * 128 + cq * 4));
        float4 b0q = *((const float4*)(b0 + cq * 4));
        const float* sA0f = (const float*)sA0;
        #pragma unroll
        for (int ri = 0; ri < 16; ri++) {
            int row = rg + ri * 8;
            const float* ar = sA0f + row * 8;
            float4 h = b0q;
            #pragma unroll
            for (int j = 0; j < 5; j++) {
                float aj = ar[j];
                h.x = fmaf(aj, w0q[j].x, h.x);
                h.y = fmaf(aj, w0q[j].y, h.y);
                h.z = fmaf(aj, w0q[j].z, h.z);
                h.w = fmaf(aj, w0q[j].w, h.w);
            }
            h.x = fmaxf(h.x, 0.f); h.y = fmaxf(h.y, 0.f);
            h.z = fmaxf(h.z, 0.f); h.w = fmaxf(h.w, 0.f);
            uint2 p;
            p.x = (unsigned)f2bf(h.x) | ((unsigned)f2bf(h.y) << 16);
            p.y = (unsigned)f2bf(h.z) | ((unsigned)f2bf(h.w) << 16);
            int byteoff = (row * 256 + cq * 8) ^ ((row & 7) << 4);
            *(uint2*)(sAb + byteoff) = p;
        }
    }
    __syncthreads();

    int wave = tid >> 6, l = tid & 63;
    int lr = l & 15, lg = l >> 4;
    int rb = wave * 32;

    short8 afr[2][4];
    #pragma unroll
    for (int rt = 0; rt < 2; rt++) {
        int row = rb + rt * 16 + lr;
        #pragma unroll
        for (int ks = 0; ks < 4; ks++) {
            int byteoff = (row * 256 + ks * 64 + lg * 16) ^ ((row & 7) << 4);
            afr[rt][ks] = *(const short8*)(sAb + byteoff);
        }
    }
    f32x4 acc[2][8];
    #pragma unroll
    for (int rt = 0; rt < 2; rt++)
        #pragma unroll
        for (int ct = 0; ct < 8; ct++)
            acc[rt][ct] = (f32x4){0.f, 0.f, 0.f, 0.f};

    #pragma unroll
    for (int ct = 0; ct < 8; ct++) {
        int col = ct * 16 + lr;
        short8 bfr[4];
        #pragma unroll
        for (int ks = 0; ks < 4; ks++) {
            int byteoff = (col * 256 + ks * 64 + lg * 16) ^ ((col & 7) << 4);
            bfr[ks] = *(const short8*)(sBb + byteoff);
        }
        #pragma unroll
        for (int rt = 0; rt < 2; rt++) {
            #pragma unroll
            for (int ks = 0; ks < 4; ks++) {
                acc[rt][ct] = __builtin_amdgcn_mfma_f32_16x16x32_bf16(
                    afr[rt][ks], bfr[ks], acc[rt][ct], 0, 0, 0);
            }
        }
    }

    // epilogue: dis*256-scale, bf16, write back into own sA rows (swizzled)
    #pragma unroll
    for (int rt = 0; rt < 2; rt++) {
        #pragma unroll
        for (int i = 0; i < 4; i++) {
            int rowL = rb + rt * 16 + lg * 4 + i;
            float dsc = sDis[rowL] * T1_SCALE;
            #pragma unroll
            for (int ct = 0; ct < 8; ct++) {
                int col = ct * 16 + lr;
                int byteoff = (rowL * 256 + col * 2) ^ ((rowL & 7) << 4);
                *(unsigned short*)(sAb + byteoff) = f2bf(acc[rt][ct][i] * dsc);
            }
        }
    }
    __syncthreads();

    // copy-out with bf16 -> fp8 conversion
    #pragma unroll
    for (int it = 0; it < 8; it++) {
        int flat = tid + it * 256;
        int rowL = flat >> 4, c16 = flat & 15;
        int gr = rowBase + rowL;
        if (gr < n) {
            int byteoff = (rowL * 256 + c16 * 16) ^ ((rowL & 7) << 4);
            uint4 v = *(const uint4*)(sAb + byteoff);
            float f0 = __uint_as_float(v.x << 16), f1 = __uint_as_float(v.x & 0xFFFF0000u);
            float f2 = __uint_as_float(v.y << 16), f3 = __uint_as_float(v.y & 0xFFFF0000u);
            float f4 = __uint_as_float(v.z << 16), f5 = __uint_as_float(v.z & 0xFFFF0000u);
            float f6 = __uint_as_float(v.w << 16), f7 = __uint_as_float(v.w & 0xFFFF0000u);
            uint2 p;
            p.x = f32x4_to_fp8(f0, f1, f2, f3);
            p.y = f32x4_to_fp8(f4, f5, f6, f7);
            ((uint2*)t1f8)[(size_t)gr * 16 + c16] = p;
        }
    }
}

// --------- layer-1 aggregation (fp8, 16-deep, index-prefetch pipelined) + layer-2 dot ---------

__global__ __launch_bounds__(256) void agg1_kernel(const unsigned* __restrict__ t1f8,
                                                   const float* __restrict__ dis,
                                                   const int* __restrict__ rowptr,
                                                   const int* __restrict__ csrc,
                                                   const float* __restrict__ b1,
                                                   const float* __restrict__ w2l,
                                                   float* __restrict__ z, int n) {
    int group = threadIdx.x >> 4, lane = threadIdx.x & 15;
    int i = blockIdx.x * 16 + group;
    if (i >= n) return;
    const uint2* t2 = (const uint2*)t1f8;        // 16 x uint2 per row (8 fp8 each)
    float f[8], acc[8];
    uint2 sv = t2[(size_t)i * 16 + lane];
    fp8x4_to_f32(sv.x, f);
    fp8x4_to_f32(sv.y, f + 4);
    #pragma unroll
    for (int j = 0; j < 8; j++) acc[j] = f[j];
    int r0 = rowptr[i], r1 = rowptr[i + 1];
    int e = r0;
    int si = (e + lane < r1) ? csrc[e + lane] : 0;    // prologue: batch-0 indices
    while (e < r1) {
        int cnt = r1 - e; if (cnt > 16) cnt = 16;     // uniform within group
        uint2 vv[16];
        #pragma unroll
        for (int u = 0; u < 16; u++) {
            if (u < cnt) {
                int s = __shfl(si, u, 16);
                vv[u] = t2[(size_t)s * 16 + lane];    // 16 gathers in flight
            }
        }
        int e2 = e + 16;
        int si2 = (e2 + lane < r1) ? csrc[e2 + lane] : 0;  // prefetch next indices
        #pragma unroll
        for (int u = 0; u < 16; u++) {
            if (u < cnt) {
                fp8x4_to_f32(vv[u].x, f);
                fp8x4_to_f32(vv[u].y, f + 4);
                #pragma unroll
                for (int j = 0; j < 8; j++) acc[j] += f[j];
            }
        }
        si = si2; e = e2;
    }
    float di = dis[i];
    float dis_s = di * T1_INV_SCALE;
    float4 b4a = ((const float4*)b1)[lane * 2];
    float4 b4b = ((const float4*)b1)[lane * 2 + 1];
    float4 w4a = ((const float4*)w2l)[lane * 2];
    float4 w4b = ((const float4*)w2l)[lane * 2 + 1];
    float bb[8] = {b4a.x, b4a.y, b4a.z, b4a.w, b4b.x, b4b.y, b4b.z, b4b.w};
    float ww[8] = {w4a.x, w4a.y, w4a.z, w4a.w, w4b.x, w4b.y, w4b.z, w4b.w};
    float d = 0.f;
    #pragma unroll
    for (int j = 0; j < 8; j++) {
        float c = fmaxf(fmaf(dis_s, acc[j], bb[j]), 0.f);
        d = fmaf(c, ww[j], d);
    }
    #pragma unroll
    for (int o = 8; o > 0; o >>= 1) d += __shfl_down(d, o, 16);
    if (lane == 0) z[i] = di * d;
}

// ------- layer-2 scalar aggregation + pooling + FINAL (last-block) -------

__global__ __launch_bounds__(256) void aggz_pool_kernel(const float* __restrict__ z,
                                                        const float* __restrict__ dis,
                                                        const int* __restrict__ rowptr,
                                                        const int* __restrict__ csrc,
                                                        const int* __restrict__ batch,
                                                        const float* __restrict__ c2,
                                                        const float* __restrict__ lb,
                                                        float* __restrict__ gsum,
                                                        int* __restrict__ gcnt,
                                                        int* __restrict__ done,
                                                        float* __restrict__ out, int n) {
    __shared__ float lg[GCN_G];
    __shared__ int lc[GCN_G];
    __shared__ int sticket;
    int tid = threadIdx.x;
    lg[tid] = 0.f;
    lc[tid] = 0;
    __syncthreads();
    int i = blockIdx.x * 256 + tid;
    bool valid = i < n;
    float ndv = 0.f;
    int g = 0;
    if (valid) {
        float acc = z[i];
        int r0 = rowptr[i], r1 = rowptr[i + 1];
        int e = r0;
        for (; e + 7 < r1; e += 8) {
            int ss[8];
            #pragma unroll
            for (int u = 0; u < 8; u++) ss[u] = csrc[e + u];
            float zv[8];
            #pragma unroll
            for (int u = 0; u < 8; u++) zv[u] = z[ss[u]];
            #pragma unroll
            for (int u = 0; u < 8; u++) acc += zv[u];
        }
        for (; e < r1; e++) acc += z[csrc[e]];
        ndv = dis[i] * acc;
        g = batch[i];
    }
    int lane = tid & 63;
    int g0 = __shfl(g, 0, 64);
    bool uni = __all(g == g0) && __all(valid);
    if (uni) {
        float s = ndv;
        #pragma unroll
        for (int o = 32; o > 0; o >>= 1) s += __shfl_down(s, o, 64);
        if (lane == 0) {
            atomicAdd(&lg[g0], s);
            atomicAdd(&lc[g0], 64);
        }
    } else if (valid) {
        atomicAdd(&lg[g], ndv);
        atomicAdd(&lc[g], 1);
    }
    __syncthreads();
    float v = lg[tid];
    int c = lc[tid];
    if (v != 0.f) atomicAdd(&gsum[tid], v);
    if (c != 0) atomicAdd(&gcnt[tid], c);

    // last-block final: device-scope ticket + atomic reads
    __threadfence();
    if (tid == 0) sticket = atomicAdd(done, 1);
    __syncthreads();
    if (sticket == (int)gridDim.x - 1) {
        float sv = atomicAdd(&gsum[tid], 0.f);
        int cv = atomicAdd(&gcnt[tid], 0);
        float vv = sv / (float)max(cv, 1) + c2[0] + lb[0];
        out[tid] = 1.f / (1.f + expf(-vv));
    }
}

// ---------------- launch ----------------

extern "C" void kernel_launch(void* const* d_in, const int* in_sizes, int n_in,
                              void* d_out, int out_size, void* d_ws, size_t ws_size,
                              hipStream_t stream) {
    const float* x   = (const float*)d_in[0];
    const int*   ei  = (const int*)d_in[1];
    const int*   bat = (const int*)d_in[2];
    const float* W0  = (const float*)d_in[3];
    const float* b0  = (const float*)d_in[4];
    const float* W1  = (const float*)d_in[5];
    const float* b1  = (const float*)d_in[6];
    const float* W2  = (const float*)d_in[7];
    const float* b2  = (const float*)d_in[8];
    const float* lw  = (const float*)d_in[9];
    const float* lb  = (const float*)d_in[10];
    float* out = (float*)d_out;

    const int N = GCN_N;
    const int E = in_sizes[1] / 2;
    const int B = (E + CHUNK - 1) / CHUNK;

    char* ws = (char*)d_ws;
    size_t off = 0;
    auto alloc = [&](size_t bytes) {
        size_t o = off;
        off += (bytes + 255) & ~(size_t)255;
        return o;
    };
    int*   hist    = (int*)(ws + alloc((size_t)B * NBKT * 4));
    int*   offsT   = (int*)(ws + alloc((size_t)NBKT * B * 4));
    int*   btot    = (int*)(ws + alloc((size_t)NBKT * 4));
    int*   bbase   = (int*)(ws + alloc((size_t)(NBKT + 1) * 4));
    int*   epack   = (int*)(ws + alloc((size_t)E * 4));
    int*   rowptr  = (int*)(ws + alloc((size_t)(N + 1) * 4));
    float* dis     = (float*)(ws + alloc((size_t)N * 4));
    int*   csrc    = (int*)(ws + alloc((size_t)E * 4));
    float* xsp     = (float*)(ws + alloc((size_t)N * 8 * 4));
    float* a0p     = (float*)(ws + alloc((size_t)N * 8 * 4));
    unsigned* t1f8 = (unsigned*)(ws + alloc((size_t)N * GCN_H));
    float* z       = (float*)(ws + alloc((size_t)N * 4));
    float* w2l     = (float*)(ws + alloc(128 * 4));
    float* c2      = (float*)(ws + alloc(4));
    unsigned short* w1t = (unsigned short*)(ws + alloc(128 * 128 * 2));
    float* gsum    = (float*)(ws + alloc(GCN_G * 4));   // gsum|gcnt|done|done2 contiguous
    int*   gcnt    = (int*)(ws + alloc(GCN_G * 4));
    int*   done    = (int*)(ws + alloc(4));
    int*   done2   = (int*)(ws + alloc(4));

    const int* src = ei;
    const int* dst = ei + E;

    hipMemsetAsync(gsum, 0, GCN_G * 4 * 2 + 512, stream);   // gsum+gcnt+done+done2

    hist_prep_kernel<<<B + 65, 256, 0, stream>>>(dst, hist, E, B, W1, W2, b2, lw, w1t, w2l, c2);
    scan_cols_kernel<<<NBKT, 64, 0, stream>>>(hist, offsT, btot, bbase, rowptr, done2, B, N);
    partition_kernel<<<B, 256, 0, stream>>>(src, dst, bbase, offsT, epack, E, B);
    csr_build_kernel<<<NBKT, 512, 0, stream>>>(epack, bbase, x, rowptr, dis, xsp, csrc, N);

    aggx_kernel<<<(N + 255) / 256, 256, 0, stream>>>(xsp, dis, rowptr, csrc, a0p, N);
    mmfused_kernel<<<(N + 127) / 128, 256, 0, stream>>>(a0p, W0, b0, w1t, dis, t1f8, N);
    agg1_kernel<<<(N + 15) / 16, 256, 0, stream>>>(t1f8, dis, rowptr, csrc, b1, w2l, z, N);
    aggz_pool_kernel<<<(N + 255) / 256, 256, 0, stream>>>(z, dis, rowptr, csrc, bat, c2, lb,
                                                          gsum, gcnt, done, out, N);
}

// Round 13
// 148.543 us; speedup vs baseline: 1.2334x; 1.1820x over previous
//
#include <hip/hip_runtime.h>
#include <hip/hip_fp8.h>

#define GCN_N 100000
#define GCN_H 128
#define GCN_G 256
#define NPB_SHIFT 9                    // 512 nodes per bucket
#define NPB 512
#define NBKT 196                       // ceil(100000/512)
#define CHUNK 2048                     // edges per hist/partition block
#define SRC_BITS 17
#define SRC_MASK ((1 << SRC_BITS) - 1)
#define T1_SCALE 256.0f
#define T1_INV_SCALE (1.0f / 256.0f)
#define EBUF_CAP 10240                 // LDS staging for csr_build (avg 8192/bucket)

static_assert(GCN_N < (1 << SRC_BITS), "src id must fit 17 bits");

using short8 = __attribute__((ext_vector_type(8))) short;
using f32x4  = __attribute__((ext_vector_type(4))) float;
using f32x2  = __attribute__((ext_vector_type(2))) float;

#if defined(__has_builtin)
#if __has_builtin(__builtin_amdgcn_cvt_pk_f32_fp8) && __has_builtin(__builtin_amdgcn_cvt_pk_fp8_f32)
#define HW_FP8 1
#endif
#endif

// ---------------- bf16 / fp8 helpers ----------------

__device__ __forceinline__ unsigned short f2bf(float f) {
    unsigned u = __float_as_uint(f);
    unsigned r = u + 0x7FFFu + ((u >> 16) & 1u);   // round to nearest even
    return (unsigned short)(r >> 16);
}
__device__ __forceinline__ float bf2f(unsigned short h) {
    return __uint_as_float(((unsigned)h) << 16);
}

__device__ __forceinline__ void fp8x4_to_f32(unsigned v, float* f) {
#ifdef HW_FP8
    f32x2 lo = __builtin_amdgcn_cvt_pk_f32_fp8((int)v, false);
    f32x2 hi = __builtin_amdgcn_cvt_pk_f32_fp8((int)v, true);
    f[0] = lo[0]; f[1] = lo[1]; f[2] = hi[0]; f[3] = hi[1];
#else
    #pragma unroll
    for (int j = 0; j < 4; j++) {
        __hip_fp8_e4m3 h;
        h.__x = (unsigned char)((v >> (8 * j)) & 0xFF);
        f[j] = (float)h;
    }
#endif
}

__device__ __forceinline__ unsigned f32x4_to_fp8(float f0, float f1, float f2, float f3) {
#ifdef HW_FP8
    int r = __builtin_amdgcn_cvt_pk_fp8_f32(f0, f1, 0, false);
    r = __builtin_amdgcn_cvt_pk_fp8_f32(f2, f3, r, true);
    return (unsigned)r;
#else
    unsigned r = 0;
    float ff[4] = {f0, f1, f2, f3};
    #pragma unroll
    for (int j = 0; j < 4; j++) {
        __hip_fp8_e4m3 h(ff[j]);
        r |= ((unsigned)h.__x) << (8 * j);
    }
    return r;
#endif
}

// ---------------- CSR build: atomic-free radix partition ----------------

__global__ __launch_bounds__(256) void hist_kernel(const int* __restrict__ dst,
                                                   int* __restrict__ hist, int E) {
    __shared__ int lh[NBKT];
    int tid = threadIdx.x;
    if (tid < NBKT) lh[tid] = 0;
    __syncthreads();
    int e0 = blockIdx.x * CHUNK;
    #pragma unroll
    for (int i = 0; i < CHUNK / 256; i++) {
        int e = e0 + tid + i * 256;
        if (e < E) atomicAdd(&lh[dst[e] >> NPB_SHIFT], 1);
    }
    __syncthreads();
    if (tid < NBKT) hist[(size_t)blockIdx.x * NBKT + tid] = lh[tid];
}

__global__ __launch_bounds__(64) void scan_cols_kernel(const int* __restrict__ hist,
                                                       int* __restrict__ offsT,
                                                       int* __restrict__ btot, int B) {
    int k = blockIdx.x;
    int lane = threadIdx.x;
    int running = 0;
    for (int b0 = 0; b0 < B; b0 += 64) {
        int b = b0 + lane;
        int v = (b < B) ? hist[(size_t)b * NBKT + k] : 0;
        int iv = v;
        #pragma unroll
        for (int d = 1; d < 64; d <<= 1) {
            int x = __shfl_up(iv, d, 64);
            if (lane >= d) iv += x;
        }
        if (b < B) offsT[(size_t)k * B + b] = running + iv - v;   // exclusive
        running += __shfl(iv, 63, 64);
    }
    if (lane == 0) btot[k] = running;
}

// fused prep: blocks 0..63 = W1^T->bf16; block 64 = w2l+c2; block 65 = bucket_base
__global__ __launch_bounds__(256) void prep_kernel(const float* __restrict__ W1,
                                                   const float* __restrict__ W2,
                                                   const float* __restrict__ b2,
                                                   const float* __restrict__ lw,
                                                   const int* __restrict__ btot,
                                                   unsigned short* __restrict__ w1t,
                                                   float* __restrict__ w2l,
                                                   float* __restrict__ c2,
                                                   int* __restrict__ bbase,
                                                   int* __restrict__ rowptr, int n) {
    __shared__ float slw[128];
    int blk = blockIdx.x, tid = threadIdx.x;
    if (blk < 64) {
        int idx = blk * 256 + tid;                 // 0..16383
        int col = idx >> 7, k = idx & 127;
        w1t[idx] = f2bf(W1[k * 128 + col]);
    } else if (blk == 64) {
        if (tid < 128) slw[tid] = lw[tid];
        __syncthreads();
        if (tid < 128) {
            float s = 0.f;
            #pragma unroll 8
            for (int j = 0; j < 128; j++) s = fmaf(W2[tid * 128 + j], slw[j], s);
            w2l[tid] = s;
        } else if (tid == 128) {
            float s = 0.f;
            for (int j = 0; j < 128; j++) s = fmaf(b2[j], slw[j], s);
            c2[0] = s;
        }
    } else {
        // 64-lane parallel exclusive scan of btot -> bbase (single wave)
        if (tid < 64) {
            int lane = tid;
            int run = 0;
            for (int b0 = 0; b0 < NBKT; b0 += 64) {
                int kk = b0 + lane;
                int v = (kk < NBKT) ? btot[kk] : 0;
                int iv = v;
                #pragma unroll
                for (int d = 1; d < 64; d <<= 1) {
                    int x = __shfl_up(iv, d, 64);
                    if (lane >= d) iv += x;
                }
                if (kk < NBKT) bbase[kk] = run + iv - v;
                run += __shfl(iv, 63, 64);
            }
            if (lane == 0) { bbase[NBKT] = run; rowptr[n] = run; }
        }
    }
}

__global__ __launch_bounds__(256) void partition_kernel(const int* __restrict__ src,
                                                        const int* __restrict__ dst,
                                                        const int* __restrict__ bbase,
                                                        const int* __restrict__ offsT,
                                                        int* __restrict__ epack,
                                                        int E, int B) {
    __shared__ int cur[NBKT];
    int blk = blockIdx.x, tid = threadIdx.x;
    if (tid < NBKT) cur[tid] = bbase[tid] + offsT[(size_t)tid * B + blk];
    __syncthreads();
    int e0 = blk * CHUNK;
    #pragma unroll
    for (int i = 0; i < CHUNK / 256; i++) {
        int e = e0 + tid + i * 256;
        if (e < E) {
            int d = dst[e];
            int s = src[e];
            int pos = atomicAdd(&cur[d >> NPB_SHIFT], 1);
            epack[pos] = ((d & (NPB - 1)) << SRC_BITS) | s;
        }
    }
}

// builds local CSR AND writes dis + xsp (fused xscale); LDS-stages its epack slice
__global__ __launch_bounds__(512) void csr_build_kernel(const int* __restrict__ epack,
                                                        const int* __restrict__ bbase,
                                                        const float* __restrict__ x,
                                                        int* __restrict__ rowptr,
                                                        float* __restrict__ dis,
                                                        float* __restrict__ xsp,
                                                        int* __restrict__ csrc, int n) {
    __shared__ int ebuf[EBUF_CAP];              // 40 KB
    __shared__ int lcount[NPB];
    __shared__ int lcur[NPB];
    __shared__ int wsums[8];
    int k = blockIdx.x, tid = threadIdx.x;
    int lane = tid & 63, wid = tid >> 6;
    int nodebase = k << NPB_SHIFT;
    int ebeg = bbase[k], eend = bbase[k + 1];
    bool fits = (eend - ebeg) <= EBUF_CAP;

    lcount[tid] = 0;
    __syncthreads();
    for (int e = ebeg + tid; e < eend; e += 512) {
        int p = epack[e];
        if (fits) ebuf[e - ebeg] = p;
        atomicAdd(&lcount[p >> SRC_BITS], 1);
    }
    __syncthreads();

    int v = lcount[tid];
    int iv = v;
    #pragma unroll
    for (int d = 1; d < 64; d <<= 1) {
        int x2 = __shfl_up(iv, d, 64);
        if (lane >= d) iv += x2;
    }
    if (lane == 63) wsums[wid] = iv;
    __syncthreads();
    if (tid == 0) {
        int r = 0;
        #pragma unroll
        for (int w = 0; w < 8; w++) { int t = wsums[w]; wsums[w] = r; r += t; }
    }
    __syncthreads();
    int ex = wsums[wid] + iv - v;
    lcur[tid] = ex;
    int node = nodebase + tid;
    if (node < n) {
        rowptr[node] = ebeg + ex;
        float dd = rsqrtf((float)(v + 1));       // deg = indeg + self-loop
        dis[node] = dd;
        const float* xr = x + (size_t)node * 5;
        float4 a;
        a.x = xr[0] * dd; a.y = xr[1] * dd; a.z = xr[2] * dd; a.w = xr[3] * dd;
        float a4 = xr[4] * dd;
        ((float4*)(xsp + (size_t)node * 8))[0] = a;
        xsp[(size_t)node * 8 + 4] = a4;
        xsp[(size_t)node * 8 + 5] = 0.f;
        xsp[(size_t)node * 8 + 6] = 0.f;
        xsp[(size_t)node * 8 + 7] = 0.f;
    }
    __syncthreads();
    for (int e = ebeg + tid; e < eend; e += 512) {
        int p = fits ? ebuf[e - ebeg] : epack[e];
        int pos = atomicAdd(&lcur[p >> SRC_BITS], 1);
        csrc[ebeg + pos] = p & SRC_MASK;
    }
}

// ---------------- layer-0 aggregation (5-dim, 8-deep prefetch) ----------------

__global__ __launch_bounds__(256) void aggx_kernel(const float* __restrict__ xsp,
                                                   const float* __restrict__ dis,
                                                   const int* __restrict__ rowptr,
                                                   const int* __restrict__ csrc,
                                                   float* __restrict__ a0p, int n) {
    int i = blockIdx.x * 256 + threadIdx.x;
    if (i >= n) return;
    float4 acc = ((const float4*)(xsp + (size_t)i * 8))[0];
    float acc4 = xsp[(size_t)i * 8 + 4];
    int r0 = rowptr[i], r1 = rowptr[i + 1];
    int e = r0;
    for (; e + 7 < r1; e += 8) {
        int ss[8];
        #pragma unroll
        for (int u = 0; u < 8; u++) ss[u] = csrc[e + u];
        float4 v[8]; float a4[8];
        #pragma unroll
        for (int u = 0; u < 8; u++) {
            v[u] = ((const float4*)(xsp + (size_t)ss[u] * 8))[0];
            a4[u] = xsp[(size_t)ss[u] * 8 + 4];
        }
        #pragma unroll
        for (int u = 0; u < 8; u++) {
            acc.x += v[u].x; acc.y += v[u].y; acc.z += v[u].z; acc.w += v[u].w;
            acc4 += a4[u];
        }
    }
    for (; e < r1; e++) {
        int s = csrc[e];
        float4 v = ((const float4*)(xsp + (size_t)s * 8))[0];
        acc.x += v.x; acc.y += v.y; acc.z += v.z; acc.w += v.w;
        acc4 += xsp[(size_t)s * 8 + 4];
    }
    float di = dis[i];
    acc.x *= di; acc.y *= di; acc.z *= di; acc.w *= di; acc4 *= di;
    ((float4*)(a0p + (size_t)i * 8))[0] = acc;
    a0p[(size_t)i * 8 + 4] = acc4;
}

// ------- fused mm (MFMA): t1 = fp8( 256 * dis ⊙ (relu(a0@W0 + b0) @ W1) ) -------

__global__ __launch_bounds__(256) void mmfused_kernel(const float* __restrict__ a0p,
                                                      const float* __restrict__ W0,
                                                      const float* __restrict__ b0,
                                                      const unsigned short* __restrict__ w1t,
                                                      const float* __restrict__ dis,
                                                      unsigned* __restrict__ t1f8, int n) {
    __shared__ __align__(16) unsigned short sA[128 * 128];   // 32 KB h1 / reused for out
    __shared__ __align__(16) unsigned short sBT[128 * 128];  // 32 KB W1^T
    __shared__ __align__(16) float4 sA0[256];                // 4 KB a0p rows
    __shared__ float sDis[128];
    char* sAb = (char*)sA;
    char* sBb = (char*)sBT;
    int tid = threadIdx.x;
    int rowBase = blockIdx.x * 128;

    {
        int rowL = tid >> 1, q = tid & 1;
        int gr = rowBase + rowL;
        float4 v = make_float4(0.f, 0.f, 0.f, 0.f);
        if (gr < n) v = ((const float4*)a0p)[(size_t)gr * 2 + q];
        sA0[tid] = v;
        if (tid < 128) {
            int g2 = rowBase + tid;
            sDis[tid] = (g2 < n) ? dis[g2] : 0.f;
        }
    }
    #pragma unroll
    for (int it = 0; it < 8; it++) {
        int idx = tid + it * 256;           // uint4 index, 0..2047
        int col = idx >> 4, c = idx & 15;   // c: 16B chunk = 8 k-values
        uint4 v = ((const uint4*)w1t)[idx];
        int byteoff = (col * 256 + c * 16) ^ ((col & 7) << 4);
        *(uint4*)(sBb + byteoff) = v;
    }
    __syncthreads();

    {
        int cq = tid & 31;          // col quad: cols cq*4..cq*4+3
        int rg = tid >> 5;          // row group 0..7
        float4 w0q[5];
        #pragma unroll
        for (int j = 0; j < 5; j++) w0q[j] = *((const float4*)(W0 + j * 128 + cq * 4));
        float4 b0q = *((const float4*)(b0 + cq * 4));
        const float* sA0f = (const float*)sA0;
        #pragma unroll
        for (int ri = 0; ri < 16; ri++) {
            int row = rg + ri * 8;
            const float* ar = sA0f + row * 8;
            float4 h = b0q;
            #pragma unroll
            for (int j = 0; j < 5; j++) {
                float aj = ar[j];
                h.x = fmaf(aj, w0q[j].x, h.x);
                h.y = fmaf(aj, w0q[j].y, h.y);
                h.z = fmaf(aj, w0q[j].z, h.z);
                h.w = fmaf(aj, w0q[j].w, h.w);
            }
            h.x = fmaxf(h.x, 0.f); h.y = fmaxf(h.y, 0.f);
            h.z = fmaxf(h.z, 0.f); h.w = fmaxf(h.w, 0.f);
            uint2 p;
            p.x = (unsigned)f2bf(h.x) | ((unsigned)f2bf(h.y) << 16);
            p.y = (unsigned)f2bf(h.z) | ((unsigned)f2bf(h.w) << 16);
            int byteoff = (row * 256 + cq * 8) ^ ((row & 7) << 4);
            *(uint2*)(sAb + byteoff) = p;
        }
    }
    __syncthreads();

    int wave = tid >> 6, l = tid & 63;
    int lr = l & 15, lg = l >> 4;
    int rb = wave * 32;

    short8 afr[2][4];
    #pragma unroll
    for (int rt = 0; rt < 2; rt++) {
        int row = rb + rt * 16 + lr;
        #pragma unroll
        for (int ks = 0; ks < 4; ks++) {
            int byteoff = (row * 256 + ks * 64 + lg * 16) ^ ((row & 7) << 4);
            afr[rt][ks] = *(const short8*)(sAb + byteoff);
        }
    }
    f32x4 acc[2][8];
    #pragma unroll
    for (int rt = 0; rt < 2; rt++)
        #pragma unroll
        for (int ct = 0; ct < 8; ct++)
            acc[rt][ct] = (f32x4){0.f, 0.f, 0.f, 0.f};

    #pragma unroll
    for (int ct = 0; ct < 8; ct++) {
        int col = ct * 16 + lr;
        short8 bfr[4];
        #pragma unroll
        for (int ks = 0; ks < 4; ks++) {
            int byteoff = (col * 256 + ks * 64 + lg * 16) ^ ((col & 7) << 4);
            bfr[ks] = *(const short8*)(sBb + byteoff);
        }
        #pragma unroll
        for (int rt = 0; rt < 2; rt++) {
            #pragma unroll
            for (int ks = 0; ks < 4; ks++) {
                acc[rt][ct] = __builtin_amdgcn_mfma_f32_16x16x32_bf16(
                    afr[rt][ks], bfr[ks], acc[rt][ct], 0, 0, 0);
            }
        }
    }

    // epilogue: dis*256-scale, bf16, write back into own sA rows (swizzled)
    #pragma unroll
    for (int rt = 0; rt < 2; rt++) {
        #pragma unroll
        for (int i = 0; i < 4; i++) {
            int rowL = rb + rt * 16 + lg * 4 + i;
            float dsc = sDis[rowL] * T1_SCALE;
            #pragma unroll
            for (int ct = 0; ct < 8; ct++) {
                int col = ct * 16 + lr;
                int byteoff = (rowL * 256 + col * 2) ^ ((rowL & 7) << 4);
                *(unsigned short*)(sAb + byteoff) = f2bf(acc[rt][ct][i] * dsc);
            }
        }
    }
    __syncthreads();

    // copy-out with bf16 -> fp8 conversion
    #pragma unroll
    for (int it = 0; it < 8; it++) {
        int flat = tid + it * 256;
        int rowL = flat >> 4, c16 = flat & 15;
        int gr = rowBase + rowL;
        if (gr < n) {
            int byteoff = (rowL * 256 + c16 * 16) ^ ((rowL & 7) << 4);
            uint4 v = *(const uint4*)(sAb + byteoff);
            float f0 = __uint_as_float(v.x << 16), f1 = __uint_as_float(v.x & 0xFFFF0000u);
            float f2 = __uint_as_float(v.y << 16), f3 = __uint_as_float(v.y & 0xFFFF0000u);
            float f4 = __uint_as_float(v.z << 16), f5 = __uint_as_float(v.z & 0xFFFF0000u);
            float f6 = __uint_as_float(v.w << 16), f7 = __uint_as_float(v.w & 0xFFFF0000u);
            uint2 p;
            p.x = f32x4_to_fp8(f0, f1, f2, f3);
            p.y = f32x4_to_fp8(f4, f5, f6, f7);
            ((uint2*)t1f8)[(size_t)gr * 16 + c16] = p;
        }
    }
}

// --------- layer-1 aggregation (fp8, shuffle-batched 16-deep gather) + layer-2 dot ---------

__global__ __launch_bounds__(256) void agg1_kernel(const unsigned* __restrict__ t1f8,
                                                   const float* __restrict__ dis,
                                                   const int* __restrict__ rowptr,
                                                   const int* __restrict__ csrc,
                                                   const float* __restrict__ b1,
                                                   const float* __restrict__ w2l,
                                                   float* __restrict__ z, int n) {
    int group = threadIdx.x >> 4, lane = threadIdx.x & 15;
    int i = blockIdx.x * 16 + group;
    if (i >= n) return;
    const uint2* t2 = (const uint2*)t1f8;        // 16 x uint2 per row (8 fp8 each)
    float f[8], acc[8];
    uint2 sv = t2[(size_t)i * 16 + lane];
    fp8x4_to_f32(sv.x, f);
    fp8x4_to_f32(sv.y, f + 4);
    #pragma unroll
    for (int j = 0; j < 8; j++) acc[j] = f[j];
    int r0 = rowptr[i], r1 = rowptr[i + 1];
    for (int e = r0; e < r1; e += 16) {
        int cnt = r1 - e; if (cnt > 16) cnt = 16;   // uniform within group
        int idx = e + lane;
        int si = (idx < r1) ? csrc[idx] : 0;        // coalesced index load
        uint2 vv[16];
        #pragma unroll
        for (int u = 0; u < 16; u++) {
            if (u < cnt) {
                int s = __shfl(si, u, 16);
                vv[u] = t2[(size_t)s * 16 + lane];  // 16 independent gathers in flight
            }
        }
        #pragma unroll
        for (int u = 0; u < 16; u++) {
            if (u < cnt) {
                fp8x4_to_f32(vv[u].x, f);
                fp8x4_to_f32(vv[u].y, f + 4);
                #pragma unroll
                for (int j = 0; j < 8; j++) acc[j] += f[j];
            }
        }
    }
    float di = dis[i];
    float dis_s = di * T1_INV_SCALE;
    float4 b4a = ((const float4*)b1)[lane * 2];
    float4 b4b = ((const float4*)b1)[lane * 2 + 1];
    float4 w4a = ((const float4*)w2l)[lane * 2];
    float4 w4b = ((const float4*)w2l)[lane * 2 + 1];
    float bb[8] = {b4a.x, b4a.y, b4a.z, b4a.w, b4b.x, b4b.y, b4b.z, b4b.w};
    float ww[8] = {w4a.x, w4a.y, w4a.z, w4a.w, w4b.x, w4b.y, w4b.z, w4b.w};
    float d = 0.f;
    #pragma unroll
    for (int j = 0; j < 8; j++) {
        float c = fmaxf(fmaf(dis_s, acc[j], bb[j]), 0.f);
        d = fmaf(c, ww[j], d);
    }
    #pragma unroll
    for (int o = 8; o > 0; o >>= 1) d += __shfl_down(d, o, 16);
    if (lane == 0) z[i] = di * d;
}

// ------- layer-2 scalar aggregation fused with pooling (sums AND counts) -------

__global__ __launch_bounds__(256) void aggz_pool_kernel(const float* __restrict__ z,
                                                        const float* __restrict__ dis,
                                                        const int* __restrict__ rowptr,
                                                        const int* __restrict__ csrc,
                                                        const int* __restrict__ batch,
                                                        float* __restrict__ gsum,
                                                        int* __restrict__ gcnt, int n) {
    __shared__ float lg[GCN_G];
    __shared__ int lc[GCN_G];
    int tid = threadIdx.x;
    lg[tid] = 0.f;
    lc[tid] = 0;
    __syncthreads();
    int i = blockIdx.x * 256 + tid;
    bool valid = i < n;
    float ndv = 0.f;
    int g = 0;
    if (valid) {
        float acc = z[i];
        int r0 = rowptr[i], r1 = rowptr[i + 1];
        int e = r0;
        for (; e + 7 < r1; e += 8) {
            int ss[8];
            #pragma unroll
            for (int u = 0; u < 8; u++) ss[u] = csrc[e + u];
            float zv[8];
            #pragma unroll
            for (int u = 0; u < 8; u++) zv[u] = z[ss[u]];
            #pragma unroll
            for (int u = 0; u < 8; u++) acc += zv[u];
        }
        for (; e < r1; e++) acc += z[csrc[e]];
        ndv = dis[i] * acc;
        g = batch[i];
    }
    int lane = tid & 63;
    int g0 = __shfl(g, 0, 64);
    bool uni = __all(g == g0) && __all(valid);
    if (uni) {
        float s = ndv;
        #pragma unroll
        for (int o = 32; o > 0; o >>= 1) s += __shfl_down(s, o, 64);
        if (lane == 0) {
            atomicAdd(&lg[g0], s);
            atomicAdd(&lc[g0], 64);
        }
    } else if (valid) {
        atomicAdd(&lg[g], ndv);
        atomicAdd(&lc[g], 1);
    }
    __syncthreads();
    float v = lg[tid];
    int c = lc[tid];
    if (v != 0.f) atomicAdd(&gsum[tid], v);
    if (c != 0) atomicAdd(&gcnt[tid], c);
}

// ---------------- final ----------------

__global__ __launch_bounds__(256) void final_kernel(const float* __restrict__ gsum,
                                                    const int* __restrict__ gcnt,
                                                    const float* __restrict__ c2,
                                                    const float* __restrict__ lb,
                                                    float* __restrict__ out) {
    int g = threadIdx.x;
    float cnt = (float)max(gcnt[g], 1);
    float v = gsum[g] / cnt + c2[0] + lb[0];
    out[g] = 1.f / (1.f + expf(-v));
}

// ---------------- launch ----------------

extern "C" void kernel_launch(void* const* d_in, const int* in_sizes, int n_in,
                              void* d_out, int out_size, void* d_ws, size_t ws_size,
                              hipStream_t stream) {
    const float* x   = (const float*)d_in[0];
    const int*   ei  = (const int*)d_in[1];
    const int*   bat = (const int*)d_in[2];
    const float* W0  = (const float*)d_in[3];
    const float* b0  = (const float*)d_in[4];
    const float* W1  = (const float*)d_in[5];
    const float* b1  = (const float*)d_in[6];
    const float* W2  = (const float*)d_in[7];
    const float* b2  = (const float*)d_in[8];
    const float* lw  = (const float*)d_in[9];
    const float* lb  = (const float*)d_in[10];
    float* out = (float*)d_out;

    const int N = GCN_N;
    const int E = in_sizes[1] / 2;
    const int B = (E + CHUNK - 1) / CHUNK;

    char* ws = (char*)d_ws;
    size_t off = 0;
    auto alloc = [&](size_t bytes) {
        size_t o = off;
        off += (bytes + 255) & ~(size_t)255;
        return o;
    };
    int*   hist    = (int*)(ws + alloc((size_t)B * NBKT * 4));
    int*   offsT   = (int*)(ws + alloc((size_t)NBKT * B * 4));
    int*   btot    = (int*)(ws + alloc((size_t)NBKT * 4));
    int*   bbase   = (int*)(ws + alloc((size_t)(NBKT + 1) * 4));
    int*   epack   = (int*)(ws + alloc((size_t)E * 4));
    int*   rowptr  = (int*)(ws + alloc((size_t)(N + 1) * 4));
    float* dis     = (float*)(ws + alloc((size_t)N * 4));
    int*   csrc    = (int*)(ws + alloc((size_t)E * 4));
    float* xsp     = (float*)(ws + alloc((size_t)N * 8 * 4));
    float* a0p     = (float*)(ws + alloc((size_t)N * 8 * 4));
    unsigned* t1f8 = (unsigned*)(ws + alloc((size_t)N * GCN_H));
    float* z       = (float*)(ws + alloc((size_t)N * 4));
    float* w2l     = (float*)(ws + alloc(128 * 4));
    float* c2      = (float*)(ws + alloc(4));
    unsigned short* w1t = (unsigned short*)(ws + alloc(128 * 128 * 2));
    float* gsum    = (float*)(ws + alloc(GCN_G * 4));   // contiguous with gcnt
    int*   gcnt    = (int*)(ws + alloc(GCN_G * 4));

    const int* src = ei;
    const int* dst = ei + E;

    hipMemsetAsync(gsum, 0, GCN_G * 4 * 2, stream);     // gsum + gcnt

    hist_kernel<<<B, 256, 0, stream>>>(dst, hist, E);
    scan_cols_kernel<<<NBKT, 64, 0, stream>>>(hist, offsT, btot, B);
    prep_kernel<<<66, 256, 0, stream>>>(W1, W2, b2, lw, btot, w1t, w2l, c2, bbase, rowptr, N);
    partition_kernel<<<B, 256, 0, stream>>>(src, dst, bbase, offsT, epack, E, B);
    csr_build_kernel<<<NBKT, 512, 0, stream>>>(epack, bbase, x, rowptr, dis, xsp, csrc, N);

    aggx_kernel<<<(N + 255) / 256, 256, 0, stream>>>(xsp, dis, rowptr, csrc, a0p, N);
    mmfused_kernel<<<(N + 127) / 128, 256, 0, stream>>>(a0p, W0, b0, w1t, dis, t1f8, N);
    agg1_kernel<<<(N + 15) / 16, 256, 0, stream>>>(t1f8, dis, rowptr, csrc, b1, w2l, z, N);
    aggz_pool_kernel<<<(N + 255) / 256, 256, 0, stream>>>(z, dis, rowptr, csrc, bat, gsum, gcnt, N);

    final_kernel<<<1, 256, 0, stream>>>(gsum, gcnt, c2, lb, out);
}